// Round 12
// baseline (48.065 us; speedup 1.0000x reference)
//
#include <hip/hip_runtime.h>

// KDA state update:
//   coef[e]     = beta * (v[e] - sum_d alpha[d]*k[d]*S[d][e])
//   S_new[d][e] = alpha[d]*S[d][e] + k[d]*coef[e]
//   o[e]        = sum_d q[d]*alpha[d]*S[d][e] + (sum_d q[d]*k[d]) * coef[e]
//
// B=64, H=32, DK=DV=128 -> 2048 heads. BARRIER-FREE WAVE-TILE STRUCTURE:
// unit of work = one wave x one 32-column quarter of one head. Lane owns
// 64 rows x 1 column of S in registers (single memory-system read of S --
// empirically mandatory, rounds 6-9: any re-read doubles HBM fetch). The
// d-reduction closes with ONE shfl_xor(32); per-row vector values (alpha*k,
// q*alpha, alpha, k) come from preloaded registers via __shfl. ZERO LDS,
// ZERO barriers: waves run fully independently and each processes 2 tiles
// back-to-back, so next-tile loads stream out right behind current-tile
// stores -> continuous mixed read/write stream (copy-like), instead of
// chip-wide alternating read/write phases. NT stores on Sout (champion
// policy). o via the fused algebra, so pass 2 is pure compute+store.

#define DK 128
#define DV 128

__global__ __launch_bounds__(256) void kda_update_kernel(
    const float* __restrict__ S,
    const float* __restrict__ k,
    const float* __restrict__ v,
    const float* __restrict__ q,
    const float* __restrict__ alpha,
    const float* __restrict__ beta,
    float* __restrict__ Sout,
    float* __restrict__ o)
{
    const int wid  = threadIdx.x >> 6;   // 0..3 : quarter index (column group)
    const int lane = threadIdx.x & 63;
    const int h    = lane >> 5;          // row half: 0 or 1
    const int c    = lane & 31;          // column within quarter
    const int e    = wid * 32 + c;       // this lane's column

    #pragma unroll
    for (int t = 0; t < 2; ++t) {
        const int bh = blockIdx.x * 2 + t;
        const size_t vecb = (size_t)bh * DK;
        const size_t hoff = (size_t)bh * DK * DV;

        // ---- Preload this half's per-row vectors into registers.
        // Lane (h,c) holds values for d = h*64 + j*32 + c, j in {0,1}.
        float k2[2], a2[2], q2[2];
        #pragma unroll
        for (int j = 0; j < 2; ++j) {
            const int d = h * 64 + j * 32 + c;
            k2[j] = k[vecb + d];
            a2[j] = alpha[vecb + d];
            q2[j] = q[vecb + d];
        }
        float akp[2], qap[2];
        akp[0] = k2[0] * a2[0];  akp[1] = k2[1] * a2[1];
        qap[0] = q2[0] * a2[0];  qap[1] = q2[1] * a2[1];

        // qk = sum_d q[d]*k[d] : full-wave reduce of per-lane partials.
        float qk = q2[0] * k2[0] + q2[1] * k2[1];
        qk += __shfl_xor(qk, 32);
        qk += __shfl_xor(qk, 16);
        qk += __shfl_xor(qk, 8);
        qk += __shfl_xor(qk, 4);
        qk += __shfl_xor(qk, 2);
        qk += __shfl_xor(qk, 1);

        const float vv  = v[(size_t)bh * DV + e];
        const float bet = beta[bh];

        const float* __restrict__ Sbh = S + hoff + e;

        // ---- Pass 1: load 64 rows of column e (single read, held in regs);
        //      accumulate kts and qas thread-locally.
        float s[64];
        float kts = 0.f, qas = 0.f;
        #pragma unroll
        for (int i = 0; i < 64; ++i) {
            const int d = h * 64 + i;
            s[i] = Sbh[(size_t)d * DV];
            const int src = (h << 5) | (i & 31);
            const float ak = __shfl(akp[i >> 5], src);
            const float qa = __shfl(qap[i >> 5], src);
            kts += ak * s[i];
            qas += qa * s[i];
        }
        // Close the d-reduction across the two row-halves.
        kts += __shfl_xor(kts, 32);
        qas += __shfl_xor(qas, 32);

        const float coef = bet * (vv - kts);

        // o needs no second pass: o[e] = qas + qk*coef.
        if (h == 0) {
            o[(size_t)bh * DV + e] = qas + qk * coef;
        }

        // ---- Pass 2: pure compute + nt store from registers.
        float* __restrict__ Sobh = Sout + hoff + e;
        #pragma unroll
        for (int i = 0; i < 64; ++i) {
            const int d = h * 64 + i;
            const int src = (h << 5) | (i & 31);
            const float aa = __shfl(a2[i >> 5], src);
            const float kk = __shfl(k2[i >> 5], src);
            const float sn = aa * s[i] + kk * coef;
            __builtin_nontemporal_store(sn, Sobh + (size_t)d * DV);
        }
    }
}

extern "C" void kernel_launch(void* const* d_in, const int* in_sizes, int n_in,
                              void* d_out, int out_size, void* d_ws, size_t ws_size,
                              hipStream_t stream) {
    const float* S     = (const float*)d_in[0];
    const float* k     = (const float*)d_in[1];
    const float* v     = (const float*)d_in[2];
    const float* q     = (const float*)d_in[3];
    const float* alpha = (const float*)d_in[4];
    const float* beta  = (const float*)d_in[5];

    const int BH = in_sizes[5];  // beta has B*H elements -> 2048 heads

    float* Sout = (float*)d_out;
    float* o    = Sout + (size_t)BH * DK * DV;

    kda_update_kernel<<<dim3(BH / 2), dim3(256), 0, stream>>>(S, k, v, q, alpha, beta, Sout, o);
}

// Round 13
// 47.394 us; speedup vs baseline: 1.0141x; 1.0141x over previous
//
#include <hip/hip_runtime.h>

// KDA state update:
//   coef[e]     = beta * (v[e] - sum_d alpha[d]*k[d]*S[d][e])
//   S_new[d][e] = alpha[d]*S[d][e] + k[d]*coef[e]
//   o[e]        = sum_d q[d]*alpha[d]*S[d][e] + (sum_d q[d]*k[d]) * coef[e]
//
// B=64, H=32, DK=DV=128 -> 2048 heads. CROSS-HEAD PIPELINED version of the
// round-3/5 champion structure: 256-thread block, 16-row x 4-col float4
// register tile, single memory-system read of S (mandatory: rounds 6-9 show
// any re-read doubles HBM fetch). Each block handles TWO heads; head 1's
// tile loads (with fused kts/qas accumulation) are issued BEFORE head 0's
// pass-2 nt-stores, so the store stream drains while the next load stream is
// in flight -> read/write mixing instead of alternating phases. o is fused
// into pass 1 (o = qas + qk*coef, qk via wave shuffles at stage time), so
// pass 2 is pure compute+store. Scalar red arrays (the R3 zero-conflict
// pattern; R11's v2f variant conflicted).

#define DK 128
#define DV 128

typedef float v4f __attribute__((ext_vector_type(4)));

__global__ __launch_bounds__(256) void kda_update_kernel(
    const float* __restrict__ S,
    const float* __restrict__ k,
    const float* __restrict__ v,
    const float* __restrict__ q,
    const float* __restrict__ alpha,
    const float* __restrict__ beta,
    float* __restrict__ Sout,
    float* __restrict__ o)
{
    const int tid  = threadIdx.x;
    const int col4 = (tid & 31) * 4;   // this thread's 4 columns
    const int rgrp = tid >> 5;         // 0..7 : rows rgrp*16 .. rgrp*16+15
    const int d0   = rgrp * 16;

    __shared__ float sa[2][DK];
    __shared__ float sk[2][DK];
    __shared__ float sak[2][DK];       // alpha*k
    __shared__ float sqa[2][DK];       // q*alpha
    __shared__ float scoef[DV];
    __shared__ float redk[8][DV];
    __shared__ float redq[8][DV];
    __shared__ float sqk[2][2];        // per-head, per-wave-half partial q.k

    const int bh0 = blockIdx.x * 2;

    // ---- Stage vectors for BOTH heads; per-head qk via wave reduction.
    {
        const int t  = tid >> 7;       // head select
        const int i  = tid & 127;      // element index
        const int bh = bh0 + t;
        const float kk = k[(size_t)bh * DK + i];
        const float aa = alpha[(size_t)bh * DK + i];
        const float qq = q[(size_t)bh * DK + i];
        sk[t][i]  = kk;
        sa[t][i]  = aa;
        sak[t][i] = kk * aa;
        sqa[t][i] = qq * aa;
        float p = qq * kk;
        p += __shfl_xor(p, 32);
        p += __shfl_xor(p, 16);
        p += __shfl_xor(p, 8);
        p += __shfl_xor(p, 4);
        p += __shfl_xor(p, 2);
        p += __shfl_xor(p, 1);
        if ((tid & 63) == 0) sqk[t][i >> 6] = p;
    }
    __syncthreads();

    const size_t hoff0 = (size_t)bh0 * DK * DV;
    const size_t hoff1 = hoff0 + (size_t)DK * DV;
    const float* __restrict__ Sb0 = S + hoff0;
    const float* __restrict__ Sb1 = S + hoff1;

    // ---- Head 0, pass 1: load tile into regs, fused kts/qas accumulation.
    float sA[16][4];
    v4f ktsA = {0.f, 0.f, 0.f, 0.f};
    v4f qasA = {0.f, 0.f, 0.f, 0.f};
    #pragma unroll
    for (int i = 0; i < 16; ++i) {
        const int d = d0 + i;
        const v4f sv = *reinterpret_cast<const v4f*>(Sb0 + (size_t)d * DV + col4);
        sA[i][0] = sv.x; sA[i][1] = sv.y; sA[i][2] = sv.z; sA[i][3] = sv.w;
        ktsA += sak[0][d] * sv;
        qasA += sqa[0][d] * sv;
    }
    redk[rgrp][col4 + 0] = ktsA.x; redk[rgrp][col4 + 1] = ktsA.y;
    redk[rgrp][col4 + 2] = ktsA.z; redk[rgrp][col4 + 3] = ktsA.w;
    redq[rgrp][col4 + 0] = qasA.x; redq[rgrp][col4 + 1] = qasA.y;
    redq[rgrp][col4 + 2] = qasA.z; redq[rgrp][col4 + 3] = qasA.w;
    __syncthreads();

    if (tid < DV) {
        float a1 = 0.f, a2 = 0.f;
        #pragma unroll
        for (int g = 0; g < 8; ++g) { a1 += redk[g][tid]; a2 += redq[g][tid]; }
        const float coef = beta[bh0] * (v[(size_t)bh0 * DV + tid] - a1);
        scoef[tid] = coef;
        o[(size_t)bh0 * DV + tid] = a2 + (sqk[0][0] + sqk[0][1]) * coef;
    }
    __syncthreads();

    float c0 = scoef[col4 + 0];
    float c1 = scoef[col4 + 1];
    float c2 = scoef[col4 + 2];
    float c3 = scoef[col4 + 3];

    // ---- PIPELINE: issue head 1's tile loads (fused accumulation) BEFORE
    //      head 0's stores, so loads and stores are in flight together.
    float sB[16][4];
    v4f ktsB = {0.f, 0.f, 0.f, 0.f};
    v4f qasB = {0.f, 0.f, 0.f, 0.f};
    #pragma unroll
    for (int i = 0; i < 16; ++i) {
        const int d = d0 + i;
        const v4f sv = *reinterpret_cast<const v4f*>(Sb1 + (size_t)d * DV + col4);
        sB[i][0] = sv.x; sB[i][1] = sv.y; sB[i][2] = sv.z; sB[i][3] = sv.w;
        ktsB += sak[1][d] * sv;
        qasB += sqa[1][d] * sv;
    }

    // ---- Head 0, pass 2: pure compute + nt store from sA.
    {
        float* __restrict__ So0 = Sout + hoff0;
        #pragma unroll
        for (int i = 0; i < 16; ++i) {
            const int d = d0 + i;
            const float a  = sa[0][d];
            const float kk = sk[0][d];
            v4f ov;
            ov.x = a * sA[i][0] + kk * c0;
            ov.y = a * sA[i][1] + kk * c1;
            ov.z = a * sA[i][2] + kk * c2;
            ov.w = a * sA[i][3] + kk * c3;
            __builtin_nontemporal_store(ov, reinterpret_cast<v4f*>(So0 + (size_t)d * DV + col4));
        }
    }

    // ---- Head 1 reduce (red arrays free for reuse: all reads completed
    //      before the last barrier's release of the coef phase).
    redk[rgrp][col4 + 0] = ktsB.x; redk[rgrp][col4 + 1] = ktsB.y;
    redk[rgrp][col4 + 2] = ktsB.z; redk[rgrp][col4 + 3] = ktsB.w;
    redq[rgrp][col4 + 0] = qasB.x; redq[rgrp][col4 + 1] = qasB.y;
    redq[rgrp][col4 + 2] = qasB.z; redq[rgrp][col4 + 3] = qasB.w;
    __syncthreads();

    if (tid < DV) {
        float a1 = 0.f, a2 = 0.f;
        #pragma unroll
        for (int g = 0; g < 8; ++g) { a1 += redk[g][tid]; a2 += redq[g][tid]; }
        const float coef = beta[bh0 + 1] * (v[(size_t)(bh0 + 1) * DV + tid] - a1);
        scoef[tid] = coef;
        o[(size_t)(bh0 + 1) * DV + tid] = a2 + (sqk[1][0] + sqk[1][1]) * coef;
    }
    __syncthreads();

    c0 = scoef[col4 + 0];
    c1 = scoef[col4 + 1];
    c2 = scoef[col4 + 2];
    c3 = scoef[col4 + 3];

    // ---- Head 1, pass 2: pure compute + nt store from sB.
    {
        float* __restrict__ So1 = Sout + hoff1;
        #pragma unroll
        for (int i = 0; i < 16; ++i) {
            const int d = d0 + i;
            const float a  = sa[1][d];
            const float kk = sk[1][d];
            v4f ov;
            ov.x = a * sB[i][0] + kk * c0;
            ov.y = a * sB[i][1] + kk * c1;
            ov.z = a * sB[i][2] + kk * c2;
            ov.w = a * sB[i][3] + kk * c3;
            __builtin_nontemporal_store(ov, reinterpret_cast<v4f*>(So1 + (size_t)d * DV + col4));
        }
    }
}

extern "C" void kernel_launch(void* const* d_in, const int* in_sizes, int n_in,
                              void* d_out, int out_size, void* d_ws, size_t ws_size,
                              hipStream_t stream) {
    const float* S     = (const float*)d_in[0];
    const float* k     = (const float*)d_in[1];
    const float* v     = (const float*)d_in[2];
    const float* q     = (const float*)d_in[3];
    const float* alpha = (const float*)d_in[4];
    const float* beta  = (const float*)d_in[5];

    const int BH = in_sizes[5];  // beta has B*H elements -> 2048 heads

    float* Sout = (float*)d_out;
    float* o    = Sout + (size_t)BH * DK * DV;

    kda_update_kernel<<<dim3(BH / 2), dim3(256), 0, stream>>>(S, k, v, q, alpha, beta, Sout, o);
}